// Round 1
// baseline (2432.610 us; speedup 1.0000x reference)
//
#include <hip/hip_runtime.h>
#include <hip/hip_bf16.h>
#include <cstdint>

#define T_TOK 32768
#define DIMD  1024
#define HID   2048
#define HSH   1024
#define NE    4

typedef __attribute__((ext_vector_type(8))) short short8;
typedef __attribute__((ext_vector_type(4))) float f32x4;

typedef const __attribute__((address_space(1))) void* gas_ptr;
typedef __attribute__((address_space(3))) void* las_ptr;

__device__ __forceinline__ void load_lds16(const void* g, void* l) {
  __builtin_amdgcn_global_load_lds((gas_ptr)g, (las_ptr)l, 16, 0, 0);
}

__device__ __forceinline__ unsigned short bf16r(float f) {
  union { float f; uint32_t u; } c; c.f = f;
  uint32_t u = c.u;
  uint32_t r = (u + 0x7FFFu + ((u >> 16) & 1u)) >> 16;
  return (unsigned short)r;
}

// ---------------- cast x fp32 -> bf16 ----------------
__global__ __launch_bounds__(256) void cast_x_kernel(const float* __restrict__ x,
                                                     unsigned short* __restrict__ xb, int n4) {
  int i = blockIdx.x * blockDim.x + threadIdx.x;
  int stride = gridDim.x * blockDim.x;
  for (; i < n4; i += stride) {
    float4 v = ((const float4*)x)[i];
    ushort4 o;
    o.x = bf16r(v.x); o.y = bf16r(v.y); o.z = bf16r(v.z); o.w = bf16r(v.w);
    ((ushort4*)xb)[i] = o;
  }
}

// ---------------- transpose fp32 [R][C] -> bf16 [C][R] ----------------
__global__ __launch_bounds__(256) void transpose_bf16_kernel(
    const float* __restrict__ src, unsigned short* __restrict__ dst,
    int R, int C, long srcBS, long dstBS) {
  __shared__ float tile[32][33];
  const float* s = src + (long)blockIdx.z * srcBS;
  unsigned short* d = dst + (long)blockIdx.z * dstBS;
  int c0 = blockIdx.x * 32, r0 = blockIdx.y * 32;
  int tx = threadIdx.x, ty = threadIdx.y;
#pragma unroll
  for (int i = 0; i < 4; i++)
    tile[ty + i * 8][tx] = s[(long)(r0 + ty + i * 8) * C + c0 + tx];
  __syncthreads();
#pragma unroll
  for (int i = 0; i < 4; i++)
    d[(long)(c0 + ty + i * 8) * R + r0 + tx] = bf16r(tile[tx][ty + i * 8]);
}

// ---------------- gating: fp32 x, fp64 accum, top-2, atomic list build ----------------
__global__ __launch_bounds__(256) void gating_kernel(
    const float* __restrict__ x, const float* __restrict__ gw,
    int* __restrict__ list, float* __restrict__ wl, int* __restrict__ cnt) {
  int lane = threadIdx.x & 63;
  int wid = threadIdx.x >> 6;
  long t = (long)blockIdx.x * 4 + wid;
  double acc[NE] = {0.0, 0.0, 0.0, 0.0};
  const float4* xp = (const float4*)(x + t * DIMD);
#pragma unroll
  for (int i = 0; i < 4; i++) {
    float4 xv = xp[i * 64 + lane];
#pragma unroll
    for (int e = 0; e < NE; e++) {
      float4 gv = ((const float4*)(gw + e * DIMD))[i * 64 + lane];
      acc[e] += (double)xv.x * gv.x + (double)xv.y * gv.y +
                (double)xv.z * gv.z + (double)xv.w * gv.w;
    }
  }
#pragma unroll
  for (int e = 0; e < NE; e++)
#pragma unroll
    for (int s = 32; s > 0; s >>= 1) acc[e] += __shfl_xor(acc[e], s, 64);
  if (lane == 0) {
    double m = acc[0];
    for (int e = 1; e < NE; e++) if (acc[e] > m) m = acc[e];
    double p[NE]; double s = 0.0;
    for (int e = 0; e < NE; e++) { p[e] = exp(acc[e] - m); s += p[e]; }
    int e0 = 0;
    for (int e = 1; e < NE; e++) if (p[e] > p[e0]) e0 = e;
    int e1 = (e0 == 0) ? 1 : 0;
    for (int e = 0; e < NE; e++) { if (e == e0) continue; if (p[e] > p[e1]) e1 = e; }
    float w0 = (float)(p[e0] / s), w1 = (float)(p[e1] / s);
    int pos0 = atomicAdd(&cnt[e0], 1);
    list[e0 * T_TOK + pos0] = (int)t; wl[e0 * T_TOK + pos0] = w0;
    int pos1 = atomicAdd(&cnt[e1], 1);
    list[e1 * T_TOK + pos1] = (int)t; wl[e1 * T_TOK + pos1] = w1;
  }
}

// ---------------- FFN1 + SwiGLU: h = silu(A@W1)*(A@W3), bf16 out ----------------
// A: [T][K] bf16 (optionally gathered rows). Bt: [2*Hh][K] bf16 (W1^T rows 0..Hh-1, W3^T rows Hh..)
// block: 128 rows x 64 h-cols, BK=32. 4 waves (2x2), wave = 64x32.
template <bool GATHERED>
__global__ __launch_bounds__(256) void ffn1_swiglu_kernel(
    const unsigned short* __restrict__ A, const unsigned short* __restrict__ Bt,
    unsigned short* __restrict__ Hout, const int* __restrict__ list,
    const int* __restrict__ cntp, int K, int Hh) {
  __shared__ unsigned short lds[8192];  // A tile [128][32] then B tile [128][32]
  const int tid = threadIdx.x, lane = tid & 63, wid = tid >> 6;
  const int n0 = blockIdx.x * 64, m0 = blockIdx.y * 128;
  const int M = GATHERED ? *cntp : T_TOK;
  if (m0 >= M) return;

  const unsigned short* gA[2];
  const unsigned short* gB[2];
#pragma unroll
  for (int j = 0; j < 2; j++) {
    int idx = j * 256 + tid;
    int arow = idx >> 2, kblk = idx & 3;
    int r = m0 + arow;
    int gr;
    if (GATHERED) gr = (r < M) ? list[r] : list[0];
    else gr = r;
    gA[j] = A + (long)gr * K + kblk * 8;
  }
#pragma unroll
  for (int j = 0; j < 2; j++) {
    int idx = j * 256 + tid;
    int brow = idx >> 2, kblk = idx & 3;
    int gn = (brow < 64) ? (n0 + brow) : (Hh + n0 + (brow - 64));
    gB[j] = Bt + (long)gn * K + kblk * 8;
  }
  unsigned short* ldst[4];
#pragma unroll
  for (int j = 0; j < 4; j++) ldst[j] = &lds[(j * 256 + wid * 64) * 8];

  const int wm = wid >> 1, wn = wid & 1;
  const int l15 = lane & 15, l4 = lane >> 4;
  f32x4 acc1[4][2] = {};
  f32x4 acc3[4][2] = {};

  const int nk = K >> 5;
  for (int kt = 0; kt < nk; ++kt) {
    if (kt) __syncthreads();
    load_lds16(gA[0], ldst[0]);
    load_lds16(gA[1], ldst[1]);
    load_lds16(gB[0], ldst[2]);
    load_lds16(gB[1], ldst[3]);
    gA[0] += 32; gA[1] += 32; gB[0] += 32; gB[1] += 32;
    __syncthreads();
    short8 af[4], b1f[2], b3f[2];
#pragma unroll
    for (int fm = 0; fm < 4; fm++)
      af[fm] = *(const short8*)&lds[(wm * 64 + fm * 16 + l15) * 32 + l4 * 8];
#pragma unroll
    for (int fn = 0; fn < 2; fn++) {
      b1f[fn] = *(const short8*)&lds[4096 + (wn * 32 + fn * 16 + l15) * 32 + l4 * 8];
      b3f[fn] = *(const short8*)&lds[4096 + (64 + wn * 32 + fn * 16 + l15) * 32 + l4 * 8];
    }
#pragma unroll
    for (int fm = 0; fm < 4; fm++)
#pragma unroll
      for (int fn = 0; fn < 2; fn++) {
        acc1[fm][fn] = __builtin_amdgcn_mfma_f32_16x16x32_bf16(af[fm], b1f[fn], acc1[fm][fn], 0, 0, 0);
        acc3[fm][fn] = __builtin_amdgcn_mfma_f32_16x16x32_bf16(af[fm], b3f[fn], acc3[fm][fn], 0, 0, 0);
      }
  }
#pragma unroll
  for (int fm = 0; fm < 4; fm++)
#pragma unroll
    for (int fn = 0; fn < 2; fn++)
#pragma unroll
      for (int r = 0; r < 4; r++) {
        int row = m0 + wm * 64 + fm * 16 + l4 * 4 + r;
        if (!GATHERED || row < M) {
          int col = n0 + wn * 32 + fn * 16 + l15;
          float c1 = acc1[fm][fn][r], c3 = acc3[fm][fn][r];
          float hv = (c1 / (1.0f + __expf(-c1))) * c3;
          Hout[(long)row * Hh + col] = bf16r(hv);
        }
      }
}

// ---------------- FFN2: y = h @ W2 (plain store or scaled scatter-accumulate) ----------------
// A: h [*][K] bf16. Bt: [1024][K] bf16. 128x128 tile, 4 waves 2x2, wave = 64x64.
template <int MODE>  // 0: Y[row] = acc (shared); 1: Y[list[row]] += wl[row]*acc (routed)
__global__ __launch_bounds__(256) void ffn2_kernel(
    const unsigned short* __restrict__ A, const unsigned short* __restrict__ Bt,
    float* __restrict__ Y, const int* __restrict__ list, const float* __restrict__ wl,
    const int* __restrict__ cntp, int K) {
  __shared__ unsigned short lds[8192];
  const int tid = threadIdx.x, lane = tid & 63, wid = tid >> 6;
  const int n0 = blockIdx.x * 128, m0 = blockIdx.y * 128;
  const int M = MODE ? *cntp : T_TOK;
  if (m0 >= M) return;

  const unsigned short* gA[2];
  const unsigned short* gB[2];
#pragma unroll
  for (int j = 0; j < 2; j++) {
    int idx = j * 256 + tid;
    int arow = idx >> 2, kblk = idx & 3;
    gA[j] = A + (long)(m0 + arow) * K + kblk * 8;
    gB[j] = Bt + (long)(n0 + arow) * K + kblk * 8;
  }
  unsigned short* ldst[4];
#pragma unroll
  for (int j = 0; j < 4; j++) ldst[j] = &lds[(j * 256 + wid * 64) * 8];

  const int wm = wid >> 1, wn = wid & 1;
  const int l15 = lane & 15, l4 = lane >> 4;
  f32x4 acc[4][4] = {};

  const int nk = K >> 5;
  for (int kt = 0; kt < nk; ++kt) {
    if (kt) __syncthreads();
    load_lds16(gA[0], ldst[0]);
    load_lds16(gA[1], ldst[1]);
    load_lds16(gB[0], ldst[2]);
    load_lds16(gB[1], ldst[3]);
    gA[0] += 32; gA[1] += 32; gB[0] += 32; gB[1] += 32;
    __syncthreads();
    short8 af[4], bf[4];
#pragma unroll
    for (int fm = 0; fm < 4; fm++)
      af[fm] = *(const short8*)&lds[(wm * 64 + fm * 16 + l15) * 32 + l4 * 8];
#pragma unroll
    for (int fn = 0; fn < 4; fn++)
      bf[fn] = *(const short8*)&lds[4096 + (wn * 64 + fn * 16 + l15) * 32 + l4 * 8];
#pragma unroll
    for (int fm = 0; fm < 4; fm++)
#pragma unroll
      for (int fn = 0; fn < 4; fn++)
        acc[fm][fn] = __builtin_amdgcn_mfma_f32_16x16x32_bf16(af[fm], bf[fn], acc[fm][fn], 0, 0, 0);
  }
#pragma unroll
  for (int fm = 0; fm < 4; fm++)
#pragma unroll
    for (int r = 0; r < 4; r++) {
      int row = m0 + wm * 64 + fm * 16 + l4 * 4 + r;
      if (MODE == 0) {
#pragma unroll
        for (int fn = 0; fn < 4; fn++) {
          int col = n0 + wn * 64 + fn * 16 + l15;
          Y[(long)row * DIMD + col] = acc[fm][fn][r];
        }
      } else if (row < M) {
        int tok = list[row];
        float w = wl[row];
#pragma unroll
        for (int fn = 0; fn < 4; fn++) {
          int col = n0 + wn * 64 + fn * 16 + l15;
          Y[(long)tok * DIMD + col] += w * acc[fm][fn][r];
        }
      }
    }
}

// ---------------- launch ----------------
extern "C" void kernel_launch(void* const* d_in, const int* in_sizes, int n_in,
                              void* d_out, int out_size, void* d_ws, size_t ws_size,
                              hipStream_t stream) {
  const float* x  = (const float*)d_in[0];
  const float* gw = (const float*)d_in[1];
  const float* W1 = (const float*)d_in[2];
  const float* W3 = (const float*)d_in[3];
  const float* W2 = (const float*)d_in[4];
  const float* Ws1 = (const float*)d_in[5];
  const float* Ws3 = (const float*)d_in[6];
  const float* Ws2 = (const float*)d_in[7];
  float* y = (float*)d_out;

  char* ws = (char*)d_ws;
  unsigned short* xb    = (unsigned short*)(ws + 0);            //  64 MB [T][1024]
  unsigned short* wt13  = (unsigned short*)(ws + 67108864L);    //  32 MB [4][4096][1024]
  unsigned short* wt2   = (unsigned short*)(ws + 100663296L);   //  16 MB [4][1024][2048]
  unsigned short* wts13 = (unsigned short*)(ws + 117440512L);   //   4 MB [2048][1024]
  unsigned short* wts2  = (unsigned short*)(ws + 121634816L);   //   2 MB [1024][1024]
  unsigned short* hbuf  = (unsigned short*)(ws + 123731968L);   // 128 MB [T][2048]
  int*   list = (int*)(ws + 257949696L);                        // [4][T]
  float* wl   = (float*)(ws + 258473984L);                      // [4][T]
  int*   cnt  = (int*)(ws + 258998272L);                        // [4]

  hipMemsetAsync(cnt, 0, 16, stream);
  cast_x_kernel<<<4096, 256, 0, stream>>>(x, xb, T_TOK * DIMD / 4);

  // W1 [e][1024][2048] -> wt13[e] rows 0..2047 ; W3 -> rows 2048..4095
  transpose_bf16_kernel<<<dim3(64, 32, 4), dim3(32, 8), 0, stream>>>(
      W1, wt13, 1024, 2048, 1024L * 2048, 4096L * 1024);
  transpose_bf16_kernel<<<dim3(64, 32, 4), dim3(32, 8), 0, stream>>>(
      W3, wt13 + 2048L * 1024, 1024, 2048, 1024L * 2048, 4096L * 1024);
  // W2 [e][2048][1024] -> wt2[e] [1024][2048]
  transpose_bf16_kernel<<<dim3(32, 64, 4), dim3(32, 8), 0, stream>>>(
      W2, wt2, 2048, 1024, 2048L * 1024, 1024L * 2048);
  transpose_bf16_kernel<<<dim3(32, 32, 1), dim3(32, 8), 0, stream>>>(
      Ws1, wts13, 1024, 1024, 0, 0);
  transpose_bf16_kernel<<<dim3(32, 32, 1), dim3(32, 8), 0, stream>>>(
      Ws3, wts13 + 1024L * 1024, 1024, 1024, 0, 0);
  transpose_bf16_kernel<<<dim3(32, 32, 1), dim3(32, 8), 0, stream>>>(
      Ws2, wts2, 1024, 1024, 0, 0);

  gating_kernel<<<T_TOK / 4, 256, 0, stream>>>(x, gw, list, wl, cnt);

  // shared expert: h_s = silu(x@Ws1)*(x@Ws3)  [T][1024];  y = h_s @ Ws2
  ffn1_swiglu_kernel<false><<<dim3(16, 256), 256, 0, stream>>>(
      xb, wts13, hbuf, nullptr, nullptr, 1024, 1024);
  ffn2_kernel<0><<<dim3(8, 256), 256, 0, stream>>>(
      hbuf, wts2, y, nullptr, nullptr, nullptr, 1024);

  // routed experts, sequential (h buffer reuse; y RMW is race-free per expert)
  for (int e = 0; e < NE; e++) {
    ffn1_swiglu_kernel<true><<<dim3(32, 256), 256, 0, stream>>>(
        xb, wt13 + (long)e * 4096 * 1024, hbuf, list + e * T_TOK, cnt + e, 1024, 2048);
    ffn2_kernel<1><<<dim3(8, 256), 256, 0, stream>>>(
        hbuf, wt2 + (long)e * 1024 * 2048, y, list + e * T_TOK, wl + e * T_TOK, cnt + e, 2048);
  }
}

// Round 2
// 1675.579 us; speedup vs baseline: 1.4518x; 1.4518x over previous
//
#include <hip/hip_runtime.h>
#include <hip/hip_bf16.h>
#include <cstdint>

#define T_TOK 32768
#define DIMD  1024
#define HID   2048
#define HSH   1024
#define NE    4

typedef __attribute__((ext_vector_type(8))) short short8;
typedef __attribute__((ext_vector_type(4))) float f32x4;

typedef const __attribute__((address_space(1))) void* gas_ptr;
typedef __attribute__((address_space(3))) void* las_ptr;

__device__ __forceinline__ void load_lds16(const void* g, void* l) {
  __builtin_amdgcn_global_load_lds((gas_ptr)g, (las_ptr)l, 16, 0, 0);
}

__device__ __forceinline__ unsigned short bf16r(float f) {
  union { float f; uint32_t u; } c; c.f = f;
  uint32_t u = c.u;
  uint32_t r = (u + 0x7FFFu + ((u >> 16) & 1u)) >> 16;
  return (unsigned short)r;
}

// ---------------- transpose fp32 [R][C] -> bf16 [C][R] ----------------
__global__ __launch_bounds__(256) void transpose_bf16_kernel(
    const float* __restrict__ src, unsigned short* __restrict__ dst,
    int R, int C, long srcBS, long dstBS) {
  __shared__ float tile[32][33];
  const float* s = src + (long)blockIdx.z * srcBS;
  unsigned short* d = dst + (long)blockIdx.z * dstBS;
  int c0 = blockIdx.x * 32, r0 = blockIdx.y * 32;
  int tx = threadIdx.x, ty = threadIdx.y;
#pragma unroll
  for (int i = 0; i < 4; i++)
    tile[ty + i * 8][tx] = s[(long)(r0 + ty + i * 8) * C + c0 + tx];
  __syncthreads();
#pragma unroll
  for (int i = 0; i < 4; i++)
    d[(long)(c0 + ty + i * 8) * R + r0 + tx] = bf16r(tile[tx][ty + i * 8]);
}

// ---------------- gating + x cast, block-aggregated list build ----------------
// 256 threads = 4 waves; block handles 64 tokens (16 per wave).
// fp64 accumulation for top-2 ordering identical to round-1 (validated).
// Per-block: 4 atomicAdds total (one per expert) instead of 2 per token.
__global__ __launch_bounds__(256) void gating_cast_kernel(
    const float* __restrict__ x, const float* __restrict__ gw,
    unsigned short* __restrict__ xb,
    int* __restrict__ list, float* __restrict__ wl, int* __restrict__ cnt) {
  __shared__ int   se[128];    // expert id per slot (token-local*2 + k)
  __shared__ float sw[128];    // combine weight per slot
  __shared__ int   sloc[128];  // local offset within (block, expert)
  __shared__ int   sbase[NE];
  const int lane = threadIdx.x & 63;
  const int wid = threadIdx.x >> 6;
  const int tb = blockIdx.x * 64;

  for (int j = 0; j < 16; j++) {
    const int tl = wid * 16 + j;
    const long t = tb + tl;
    const float4* xp = (const float4*)(x + t * DIMD);
    double acc[NE] = {0.0, 0.0, 0.0, 0.0};
    float4 xv[4];
#pragma unroll
    for (int i = 0; i < 4; i++) {
      xv[i] = xp[i * 64 + lane];
#pragma unroll
      for (int e = 0; e < NE; e++) {
        float4 gv = ((const float4*)(gw + e * DIMD))[i * 64 + lane];
        acc[e] += (double)xv[i].x * gv.x + (double)xv[i].y * gv.y +
                  (double)xv[i].z * gv.z + (double)xv[i].w * gv.w;
      }
    }
    // fused x -> bf16 cast (same rounding as round 1)
    ushort4* xbp = (ushort4*)(xb + t * DIMD);
#pragma unroll
    for (int i = 0; i < 4; i++) {
      ushort4 o;
      o.x = bf16r(xv[i].x); o.y = bf16r(xv[i].y);
      o.z = bf16r(xv[i].z); o.w = bf16r(xv[i].w);
      xbp[i * 64 + lane] = o;
    }
#pragma unroll
    for (int e = 0; e < NE; e++)
#pragma unroll
      for (int s = 32; s > 0; s >>= 1) acc[e] += __shfl_xor(acc[e], s, 64);
    if (lane == 0) {
      double m = acc[0];
      for (int e = 1; e < NE; e++) if (acc[e] > m) m = acc[e];
      double p[NE]; double s = 0.0;
      for (int e = 0; e < NE; e++) { p[e] = exp(acc[e] - m); s += p[e]; }
      int e0 = 0;
      for (int e = 1; e < NE; e++) if (p[e] > p[e0]) e0 = e;
      int e1 = (e0 == 0) ? 1 : 0;
      for (int e = 0; e < NE; e++) { if (e == e0) continue; if (p[e] > p[e1]) e1 = e; }
      se[tl * 2]     = e0; sw[tl * 2]     = (float)(p[e0] / s);
      se[tl * 2 + 1] = e1; sw[tl * 2 + 1] = (float)(p[e1] / s);
    }
  }
  __syncthreads();
  const int tid = threadIdx.x;
  if (tid < NE) {
    int c = 0;
    for (int s = 0; s < 128; s++)
      if (se[s] == tid) sloc[s] = c++;
    sbase[tid] = atomicAdd(&cnt[tid], c);
  }
  __syncthreads();
  if (tid < 128) {
    int e = se[tid];
    int pos = sbase[e] + sloc[tid];
    list[e * T_TOK + pos] = tb + (tid >> 1);
    wl[e * T_TOK + pos] = sw[tid];
  }
}

// ---------------- FFN1 + SwiGLU: h = silu(A@W1)*(A@W3), bf16 out ----------------
// A: [T][K] bf16 (optionally gathered rows). Bt: [2*Hh][K] bf16 (W1^T rows 0..Hh-1, W3^T rows Hh..)
// block: 128 rows x 64 h-cols, BK=32. 4 waves (2x2), wave = 64x32.
template <bool GATHERED>
__global__ __launch_bounds__(256) void ffn1_swiglu_kernel(
    const unsigned short* __restrict__ A, const unsigned short* __restrict__ Bt,
    unsigned short* __restrict__ Hout, const int* __restrict__ list,
    const int* __restrict__ cntp, int K, int Hh) {
  __shared__ unsigned short lds[8192];  // A tile [128][32] then B tile [128][32]
  const int tid = threadIdx.x, lane = tid & 63, wid = tid >> 6;
  const int n0 = blockIdx.x * 64, m0 = blockIdx.y * 128;
  const int M = GATHERED ? *cntp : T_TOK;
  if (m0 >= M) return;

  const unsigned short* gA[2];
  const unsigned short* gB[2];
#pragma unroll
  for (int j = 0; j < 2; j++) {
    int idx = j * 256 + tid;
    int arow = idx >> 2, kblk = idx & 3;
    int r = m0 + arow;
    int gr;
    if (GATHERED) gr = (r < M) ? list[r] : list[0];
    else gr = r;
    gA[j] = A + (long)gr * K + kblk * 8;
  }
#pragma unroll
  for (int j = 0; j < 2; j++) {
    int idx = j * 256 + tid;
    int brow = idx >> 2, kblk = idx & 3;
    int gn = (brow < 64) ? (n0 + brow) : (Hh + n0 + (brow - 64));
    gB[j] = Bt + (long)gn * K + kblk * 8;
  }
  unsigned short* ldst[4];
#pragma unroll
  for (int j = 0; j < 4; j++) ldst[j] = &lds[(j * 256 + wid * 64) * 8];

  const int wm = wid >> 1, wn = wid & 1;
  const int l15 = lane & 15, l4 = lane >> 4;
  f32x4 acc1[4][2] = {};
  f32x4 acc3[4][2] = {};

  const int nk = K >> 5;
  for (int kt = 0; kt < nk; ++kt) {
    if (kt) __syncthreads();
    load_lds16(gA[0], ldst[0]);
    load_lds16(gA[1], ldst[1]);
    load_lds16(gB[0], ldst[2]);
    load_lds16(gB[1], ldst[3]);
    gA[0] += 32; gA[1] += 32; gB[0] += 32; gB[1] += 32;
    __syncthreads();
    short8 af[4], b1f[2], b3f[2];
#pragma unroll
    for (int fm = 0; fm < 4; fm++)
      af[fm] = *(const short8*)&lds[(wm * 64 + fm * 16 + l15) * 32 + l4 * 8];
#pragma unroll
    for (int fn = 0; fn < 2; fn++) {
      b1f[fn] = *(const short8*)&lds[4096 + (wn * 32 + fn * 16 + l15) * 32 + l4 * 8];
      b3f[fn] = *(const short8*)&lds[4096 + (64 + wn * 32 + fn * 16 + l15) * 32 + l4 * 8];
    }
#pragma unroll
    for (int fm = 0; fm < 4; fm++)
#pragma unroll
      for (int fn = 0; fn < 2; fn++) {
        acc1[fm][fn] = __builtin_amdgcn_mfma_f32_16x16x32_bf16(af[fm], b1f[fn], acc1[fm][fn], 0, 0, 0);
        acc3[fm][fn] = __builtin_amdgcn_mfma_f32_16x16x32_bf16(af[fm], b3f[fn], acc3[fm][fn], 0, 0, 0);
      }
  }
#pragma unroll
  for (int fm = 0; fm < 4; fm++)
#pragma unroll
    for (int fn = 0; fn < 2; fn++)
#pragma unroll
      for (int r = 0; r < 4; r++) {
        int row = m0 + wm * 64 + fm * 16 + l4 * 4 + r;
        if (!GATHERED || row < M) {
          int col = n0 + wn * 32 + fn * 16 + l15;
          float c1 = acc1[fm][fn][r], c3 = acc3[fm][fn][r];
          float hv = (c1 / (1.0f + __expf(-c1))) * c3;
          Hout[(long)row * Hh + col] = bf16r(hv);
        }
      }
}

// ---------------- FFN2: y = h @ W2 (plain store or scaled scatter-accumulate) ----------------
// A: h [*][K] bf16. Bt: [1024][K] bf16. 128x128 tile, 4 waves 2x2, wave = 64x64.
template <int MODE>  // 0: Y[row] = acc (shared); 1: Y[list[row]] += wl[row]*acc (routed)
__global__ __launch_bounds__(256) void ffn2_kernel(
    const unsigned short* __restrict__ A, const unsigned short* __restrict__ Bt,
    float* __restrict__ Y, const int* __restrict__ list, const float* __restrict__ wl,
    const int* __restrict__ cntp, int K) {
  __shared__ unsigned short lds[8192];
  const int tid = threadIdx.x, lane = tid & 63, wid = tid >> 6;
  const int n0 = blockIdx.x * 128, m0 = blockIdx.y * 128;
  const int M = MODE ? *cntp : T_TOK;
  if (m0 >= M) return;

  const unsigned short* gA[2];
  const unsigned short* gB[2];
#pragma unroll
  for (int j = 0; j < 2; j++) {
    int idx = j * 256 + tid;
    int arow = idx >> 2, kblk = idx & 3;
    gA[j] = A + (long)(m0 + arow) * K + kblk * 8;
    gB[j] = Bt + (long)(n0 + arow) * K + kblk * 8;
  }
  unsigned short* ldst[4];
#pragma unroll
  for (int j = 0; j < 4; j++) ldst[j] = &lds[(j * 256 + wid * 64) * 8];

  const int wm = wid >> 1, wn = wid & 1;
  const int l15 = lane & 15, l4 = lane >> 4;
  f32x4 acc[4][4] = {};

  const int nk = K >> 5;
  for (int kt = 0; kt < nk; ++kt) {
    if (kt) __syncthreads();
    load_lds16(gA[0], ldst[0]);
    load_lds16(gA[1], ldst[1]);
    load_lds16(gB[0], ldst[2]);
    load_lds16(gB[1], ldst[3]);
    gA[0] += 32; gA[1] += 32; gB[0] += 32; gB[1] += 32;
    __syncthreads();
    short8 af[4], bf[4];
#pragma unroll
    for (int fm = 0; fm < 4; fm++)
      af[fm] = *(const short8*)&lds[(wm * 64 + fm * 16 + l15) * 32 + l4 * 8];
#pragma unroll
    for (int fn = 0; fn < 4; fn++)
      bf[fn] = *(const short8*)&lds[4096 + (wn * 64 + fn * 16 + l15) * 32 + l4 * 8];
#pragma unroll
    for (int fm = 0; fm < 4; fm++)
#pragma unroll
      for (int fn = 0; fn < 4; fn++)
        acc[fm][fn] = __builtin_amdgcn_mfma_f32_16x16x32_bf16(af[fm], bf[fn], acc[fm][fn], 0, 0, 0);
  }
#pragma unroll
  for (int fm = 0; fm < 4; fm++)
#pragma unroll
    for (int r = 0; r < 4; r++) {
      int row = m0 + wm * 64 + fm * 16 + l4 * 4 + r;
      if (MODE == 0) {
#pragma unroll
        for (int fn = 0; fn < 4; fn++) {
          int col = n0 + wn * 64 + fn * 16 + l15;
          Y[(long)row * DIMD + col] = acc[fm][fn][r];
        }
      } else if (row < M) {
        int tok = list[row];
        float w = wl[row];
#pragma unroll
        for (int fn = 0; fn < 4; fn++) {
          int col = n0 + wn * 64 + fn * 16 + l15;
          Y[(long)tok * DIMD + col] += w * acc[fm][fn][r];
        }
      }
    }
}

// ---------------- launch ----------------
extern "C" void kernel_launch(void* const* d_in, const int* in_sizes, int n_in,
                              void* d_out, int out_size, void* d_ws, size_t ws_size,
                              hipStream_t stream) {
  const float* x  = (const float*)d_in[0];
  const float* gw = (const float*)d_in[1];
  const float* W1 = (const float*)d_in[2];
  const float* W3 = (const float*)d_in[3];
  const float* W2 = (const float*)d_in[4];
  const float* Ws1 = (const float*)d_in[5];
  const float* Ws3 = (const float*)d_in[6];
  const float* Ws2 = (const float*)d_in[7];
  float* y = (float*)d_out;

  char* ws = (char*)d_ws;
  unsigned short* xb    = (unsigned short*)(ws + 0);            //  64 MB [T][1024]
  unsigned short* wt13  = (unsigned short*)(ws + 67108864L);    //  32 MB [4][4096][1024]
  unsigned short* wt2   = (unsigned short*)(ws + 100663296L);   //  16 MB [4][1024][2048]
  unsigned short* wts13 = (unsigned short*)(ws + 117440512L);   //   4 MB [2048][1024]
  unsigned short* wts2  = (unsigned short*)(ws + 121634816L);   //   2 MB [1024][1024]
  unsigned short* hbuf  = (unsigned short*)(ws + 123731968L);   // 128 MB [T][2048]
  int*   list = (int*)(ws + 257949696L);                        // [4][T]
  float* wl   = (float*)(ws + 258473984L);                      // [4][T]
  int*   cnt  = (int*)(ws + 258998272L);                        // [4]

  hipMemsetAsync(cnt, 0, 16, stream);

  // W1 [e][1024][2048] -> wt13[e] rows 0..2047 ; W3 -> rows 2048..4095
  transpose_bf16_kernel<<<dim3(64, 32, 4), dim3(32, 8), 0, stream>>>(
      W1, wt13, 1024, 2048, 1024L * 2048, 4096L * 1024);
  transpose_bf16_kernel<<<dim3(64, 32, 4), dim3(32, 8), 0, stream>>>(
      W3, wt13 + 2048L * 1024, 1024, 2048, 1024L * 2048, 4096L * 1024);
  // W2 [e][2048][1024] -> wt2[e] [1024][2048]
  transpose_bf16_kernel<<<dim3(32, 64, 4), dim3(32, 8), 0, stream>>>(
      W2, wt2, 2048, 1024, 2048L * 1024, 1024L * 2048);
  transpose_bf16_kernel<<<dim3(32, 32, 1), dim3(32, 8), 0, stream>>>(
      Ws1, wts13, 1024, 1024, 0, 0);
  transpose_bf16_kernel<<<dim3(32, 32, 1), dim3(32, 8), 0, stream>>>(
      Ws3, wts13 + 1024L * 1024, 1024, 1024, 0, 0);
  transpose_bf16_kernel<<<dim3(32, 32, 1), dim3(32, 8), 0, stream>>>(
      Ws2, wts2, 1024, 1024, 0, 0);

  // fused gating + x->bf16 cast; 4 atomics per 64-token block
  gating_cast_kernel<<<T_TOK / 64, 256, 0, stream>>>(x, gw, xb, list, wl, cnt);

  // shared expert: h_s = silu(x@Ws1)*(x@Ws3)  [T][1024];  y = h_s @ Ws2
  ffn1_swiglu_kernel<false><<<dim3(16, 256), 256, 0, stream>>>(
      xb, wts13, hbuf, nullptr, nullptr, 1024, 1024);
  ffn2_kernel<0><<<dim3(8, 256), 256, 0, stream>>>(
      hbuf, wts2, y, nullptr, nullptr, nullptr, 1024);

  // routed experts, sequential (h buffer reuse; y RMW is race-free per expert)
  for (int e = 0; e < NE; e++) {
    ffn1_swiglu_kernel<true><<<dim3(32, 256), 256, 0, stream>>>(
        xb, wt13 + (long)e * 4096 * 1024, hbuf, list + e * T_TOK, cnt + e, 1024, 2048);
    ffn2_kernel<1><<<dim3(8, 256), 256, 0, stream>>>(
        hbuf, wt2 + (long)e * 1024 * 2048, y, list + e * T_TOK, wl + e * T_TOK, cnt + e, 2048);
  }
}